// Round 8
// baseline (447.005 us; speedup 1.0000x reference)
//
#include <hip/hip_runtime.h>
#include <math.h>

#define S      384
#define N0     192
#define NE     191
#define MAXADJ 16
#define E50    1.9287498e-22f   // exp(-50)

// float workspace offsets (round-5 layout)
#define OFF_W     0
#define OFF_WT    36864
#define OFF_PHIE  73728
#define OFF_MSGF  147456
#define OFF_MSGB  221184
#define OFF_MXF   294912
#define OFF_MXB   368640
#define OFF_SBT   442368
#define OFF_BASET 516096
#define OFF_U     589824
#define OFF_V     590016
#define OFF_MAXF  590400
#define OFF_MAXB  590592
#define OFF_HIF   590784
#define OFF_LOF   590976
#define OFF_HIB   591168
#define OFF_LOB   591360
#define OFF_UHI   591552
#define OFF_INT   591616
// int offsets relative to (int*)(ws + OFF_INT)
#define IOFF_DSTF 0
#define IOFF_DSTB 192
#define IOFF_CNTF 384
#define IOFF_CNTB 576
#define IOFF_ADJF 768
#define IOFF_ADJB (768 + 192*MAXADJ)
#define IOFF_SYNC (768 + 2*192*MAXADJ)   // 8 steps x 3 counters (unsigned)

// ---------------------------------------------------------------------------
__global__ __launch_bounds__(256) void k_setup(
    const int* __restrict__ E1f, const int* __restrict__ E1b,
    const float* __restrict__ cost, const float* __restrict__ constr,
    float* __restrict__ ws)
{
    int tid = blockIdx.x * 256 + threadIdx.x;
    int nt  = gridDim.x * 256;

    for (int idx = tid; idx < 192 * 192; idx += nt) {
        int k = idx / 192, s = idx % 192;
        float w = __expf(-50.f * (1.f - constr[idx]));
        ws[OFF_W + idx] = w;               // W[k][s]  (fwd GEMV weights)
        ws[OFF_WT + s * 192 + k] = w;      // WT[k][s] = W[s][k] (bwd)
    }
    for (int idx = tid; idx < 192 * S; idx += nt) {
        int j = idx / S, i = idx % S;
        ws[OFF_PHIE + idx] = (i < N0) ? -10.f * cost[j * N0 + i] : 0.f;
        ws[OFF_MSGF + idx] = 0.f;
        ws[OFF_MSGB + idx] = 0.f;
        ws[OFF_MXF + idx]  = 0.f;
        ws[OFF_MXB + idx]  = (j < NE) ? 1.f : 0.f;   // exp(0-0)=1
    }
    for (int i = tid; i < S; i += nt) ws[OFF_V + i] = 0.f;
    for (int i = tid; i < 192; i += nt) {
        ws[OFF_U + i] = 0.f;
        ws[OFF_MAXF + i] = 0.f; ws[OFF_MAXB + i] = 0.f;
        ws[OFF_HIF + i] = 0.f;  ws[OFF_LOF + i] = 0.f;
        ws[OFF_HIB + i] = (i < NE) ? 192.f : 0.f;
        ws[OFF_LOB + i] = (i < NE) ? 192.f : 0.f;
    }
    if (tid == 0) ws[OFF_UHI] = 0.f;

    int* ip = (int*)(ws + OFF_INT);
    for (int e = tid; e < 192; e += nt) {
        ip[IOFF_DSTF + e] = (e < NE) ? E1f[2 * e + 1] : 0;
        ip[IOFF_DSTB + e] = (e < NE) ? E1b[2 * e + 1] : 0;
    }
    for (int b = tid; b < 192; b += nt) {
        int cf = 0, cb = 0;
        for (int e = 0; e < NE; ++e) {
            if (E1f[2 * e + 1] == b && cf < MAXADJ) ip[IOFF_ADJF + b * MAXADJ + cf++] = e;
            if (E1b[2 * e + 1] == b && cb < MAXADJ) ip[IOFF_ADJB + b * MAXADJ + cb++] = e;
        }
        ip[IOFF_CNTF + b] = cf;
        ip[IOFF_CNTB + b] = cb;
    }
    unsigned* sc = (unsigned*)(ip + IOFF_SYNC);
    for (int i = tid; i < 24; i += nt) sc[i] = 0u;
}

// ---------------------------------------------------------------------------
// producer->consumer handoff primitives (forward-only, all blocks co-resident)
__device__ __forceinline__ void arrive(unsigned* c)
{
    asm volatile("s_waitcnt vmcnt(0)" ::: "memory");   // drain this wave's stores
    __syncthreads();                                   // all waves drained
    if (threadIdx.x == 0) {
        __threadfence();                               // L2 writeback (one wave)
        __hip_atomic_fetch_add(c, 1u, __ATOMIC_RELEASE, __HIP_MEMORY_SCOPE_AGENT);
    }
}

__device__ __forceinline__ void wait_for(unsigned* c, unsigned target)
{
    if (threadIdx.x == 0) {
        while (__hip_atomic_load(c, __ATOMIC_RELAXED, __HIP_MEMORY_SCOPE_AGENT) < target)
            __builtin_amdgcn_s_sleep(8);
        __threadfence();                               // invalidate L1/L2 before reads
    }
    __syncthreads();
}

// ---------------------------------------------------------------------------
// stage 0: per row j<192 (one wave each): gather SFT/SBT from msgs, rewrite
//          BASET/SBT, u[j] = LSE_i(BT-V). Block 48: uhi = LSE_i(-V[i]).
__device__ __forceinline__ void stage_uv1(float* __restrict__ ws, int bid)
{
    int t = threadIdx.x;
    int l = t & 63, w = t >> 6;
    const float* V = ws + OFF_V;

    if (bid == 48) {
        if (w == 0) {
            float m = -1e30f, x[6];
#pragma unroll
            for (int q = 0; q < 6; ++q) { x[q] = -V[l + 64 * q]; m = fmaxf(m, x[q]); }
#pragma unroll
            for (int o = 32; o; o >>= 1) m = fmaxf(m, __shfl_xor(m, o, 64));
            float sm = 0.f;
#pragma unroll
            for (int q = 0; q < 6; ++q) sm += __expf(x[q] - m);
#pragma unroll
            for (int o = 32; o; o >>= 1) sm += __shfl_xor(sm, o, 64);
            if (l == 0) ws[OFF_UHI] = m + __logf(sm);
        }
        return;
    }

    int j = bid * 4 + w;
    const int* ip = (const int*)(ws + OFF_INT);
    int cF = ip[IOFF_CNTF + j], cB = ip[IOFF_CNTB + j];
    const int* aF = ip + IOFF_ADJF + j * MAXADJ;
    const int* aB = ip + IOFF_ADJB + j * MAXADJ;

    float sft[6] = {0,0,0,0,0,0}, sbt[6] = {0,0,0,0,0,0};
    for (int q = 0; q < cF; ++q) {
        const float* mr = ws + OFF_MSGF + aF[q] * S;
#pragma unroll
        for (int p = 0; p < 6; ++p) sft[p] += mr[l + 64 * p];
    }
    for (int q = 0; q < cB; ++q) {
        const float* mr = ws + OFF_MSGB + aB[q] * S;
#pragma unroll
        for (int p = 0; p < 6; ++p) sbt[p] += mr[l + 64 * p];
    }

    float x[6], m = -1e30f;
#pragma unroll
    for (int p = 0; p < 6; ++p) {
        int i = l + 64 * p;
        float bt = ws[OFF_PHIE + j * S + i] + sft[p] + sbt[p];
        ws[OFF_BASET + j * S + i] = bt;
        ws[OFF_SBT + j * S + i]   = sbt[p];
        x[p] = bt - V[i];
        m = fmaxf(m, x[p]);
    }
#pragma unroll
    for (int o = 32; o; o >>= 1) m = fmaxf(m, __shfl_xor(m, o, 64));
    float sm = 0.f;
#pragma unroll
    for (int p = 0; p < 6; ++p) sm += __expf(x[p] - m);
#pragma unroll
    for (int o = 32; o; o >>= 1) sm += __shfl_xor(sm, o, 64);
    if (l == 0) ws[OFF_U + j] = m + __logf(sm);
}

// stage 1: v[i] = log( sum_{j<192} exp(BT[j][i]-u[j]) + 192*exp(-uhi) )
__device__ __forceinline__ void stage_v(float* __restrict__ ws, int bid)
{
    __shared__ float Ul[192];
    __shared__ float msh[16][17], ssh[16][17];
    int t = threadIdx.x;
    if (t < 192) Ul[t] = ws[OFF_U + t];
    __syncthreads();

    const float* BT = ws + OFF_BASET;
    int il = t & 15, jg = t >> 4;
    int i = bid * 16 + il;

    float m = -1e30f, sm = 0.f;
#pragma unroll 4
    for (int j = jg; j < 192; j += 16) {
        float x = BT[j * S + i] - Ul[j];
        float mn = fmaxf(m, x);
        sm = sm * __expf(m - mn) + __expf(x - mn);
        m = mn;
    }
    msh[jg][il] = m; ssh[jg][il] = sm;
    __syncthreads();

    if (jg == 0) {
        float M = msh[0][il], Ss = ssh[0][il];
#pragma unroll
        for (int g = 1; g < 16; ++g) {
            float m2 = msh[g][il], s2 = ssh[g][il];
            float mn = fmaxf(M, m2);
            Ss = Ss * __expf(M - mn) + s2 * __expf(m2 - mn);
            M = mn;
        }
        float xt = __logf(192.f) - ws[OFF_UHI];
        float mn = fmaxf(M, xt);
        Ss = Ss * __expf(M - mn) + __expf(xt - mn);
        ws[OFF_V + i] = mn + __logf(Ss);
    }
}

// stages 2/3: msg update with fused GEMV + colsum, one block per edge
__device__ __forceinline__ void stage_msg(float* __restrict__ ws, int e, int fwd)
{
    __shared__ float mx[192];
    __shared__ float red[256], red2[256];
    int t = threadIdx.x;
    const int* ip = (const int*)(ws + OFF_INT);

    float* MSG  = ws + (fwd ? OFF_MSGF : OFF_MSGB);
    float* MX   = ws + (fwd ? OFF_MXF  : OFF_MXB);
    const float* MXin = ws + (fwd ? OFF_MXB : OFF_MXF);
    const float* Wm   = ws + (fwd ? OFF_W   : OFF_WT);

    float mPrev = fwd ? ws[OFF_MAXB + e] : ws[OFF_MAXF + e];
    float hi    = fwd ? ws[OFF_HIB + e]  : ws[OFF_HIF + e];
    float lo    = fwd ? ws[OFF_LOB + e]  : ws[OFF_LOF + e];
    float addLo = fwd ? hi : E50 * hi;
    float yHi   = fwd ? (hi + E50 * lo) : (lo + hi);
    float lyHi  = __logf(yHi);

    int d = fwd ? ip[IOFF_DSTF + e] : ip[IOFF_DSTB + e];
    float uD = ws[OFF_U + d];
    const float* V = ws + OFF_V;

    if (t < 192) mx[t] = MXin[e * S + t];
    __syncthreads();

    float acc = 0.f;
    if (t < 192) {
#pragma unroll 8
        for (int k = 0; k < 192; ++k)
            acc += Wm[k * 192 + t] * mx[k];
    }

    int s1 = t, s2 = t + 256;
    float bt1, bt2 = 0.f;
    if (fwd) {
        bt1 = ws[OFF_BASET + d * S + s1];
        if (s2 < S) bt2 = ws[OFF_BASET + d * S + s2];
    } else {
        int cF = ip[IOFF_CNTF + d];
        const int* aF = ip + IOFF_ADJF + d * MAXADJ;
        bt1 = ws[OFF_PHIE + d * S + s1] + ws[OFF_SBT + d * S + s1];
        if (s2 < S) bt2 = ws[OFF_PHIE + d * S + s2] + ws[OFF_SBT + d * S + s2];
        for (int q = 0; q < cF; ++q) {
            const float* mr = ws + OFF_MSGF + aF[q] * S;
            bt1 += mr[s1];
            if (s2 < S) bt2 += mr[s2];
        }
    }

    float logy1 = (s1 < 192) ? __logf(acc + addLo) : lyHi;
    float x1 = 0.5f * (MSG[e * S + s1] + uD + V[s1] - bt1 + mPrev + logy1);
    float x2 = 1e30f;
    if (s2 < S) {
        x2 = 0.5f * (MSG[e * S + s2] + uD + V[s2] - bt2 + mPrev + lyHi);
        MSG[e * S + s2] = x2;
    }
    MSG[e * S + s1] = x1;

    red[t] = fminf(x1, x2);
    __syncthreads();
    for (int o = 128; o; o >>= 1) {
        if (t < o) red[t] = fminf(red[t], red[t + o]);
        __syncthreads();
    }
    float mn = red[0];
    __syncthreads();

    float mx1 = __expf(mn - x1);
    float mx2 = (s2 < S) ? __expf(mn - x2) : 0.f;
    MX[e * S + s1] = mx1;
    if (s2 < S) MX[e * S + s2] = mx2;
    if (t == 0) {
        if (fwd) ws[OFF_MAXF + e] = -mn; else ws[OFF_MAXB + e] = -mn;
    }

    red[t]  = (t < 192) ? mx1 : 0.f;
    red2[t] = ((t >= 192) ? mx1 : 0.f) + mx2;
    __syncthreads();
    for (int o = 128; o; o >>= 1) {
        if (t < o) { red[t] += red[t + o]; red2[t] += red2[t + o]; }
        __syncthreads();
    }
    if (t == 0) {
        if (fwd) { ws[OFF_LOF + e] = red[0]; ws[OFF_HIF + e] = red2[0]; }
        else     { ws[OFF_LOB + e] = red[0]; ws[OFF_HIB + e] = red2[0]; }
    }
}

// ---------------------------------------------------------------------------
// one full step: 4 stages as disjoint block ranges with spin handoffs
// blocks: [0,49) uv1 | [49,73) v | [73,264) msg_f | [264,455) msg_b
__global__ __launch_bounds__(256) void k_step(float* __restrict__ ws, int step)
{
    int* ip = (int*)(ws + OFF_INT);
    unsigned* sc = (unsigned*)(ip + IOFF_SYNC) + step * 3;
    int bid = blockIdx.x;

    if (bid < 49) {
        stage_uv1(ws, bid);
        arrive(&sc[0]);
    } else if (bid < 73) {
        wait_for(&sc[0], 49u);
        stage_v(ws, bid - 49);
        arrive(&sc[1]);
    } else if (bid < 264) {
        wait_for(&sc[1], 24u);
        stage_msg(ws, bid - 73, 1);
        arrive(&sc[2]);
    } else {
        wait_for(&sc[2], 191u);
        stage_msg(ws, bid - 264, 0);
        // kernel end is the sync for the next k_step
    }
}

// ---------------------------------------------------------------------------
__global__ __launch_bounds__(256) void k_final(const float* __restrict__ ws,
                                               float* __restrict__ out)
{
    int t = threadIdx.x;
    const int* ip = (const int*)(ws + OFF_INT);
    const float* V = ws + OFF_V;
    float uhi = ws[OFF_UHI];

    for (int a = blockIdx.x * 6; a < blockIdx.x * 6 + 6; ++a) {
        if (a < 192) {
            float ua = ws[OFF_U + a];
            int cF = ip[IOFF_CNTF + a], cB = ip[IOFF_CNTB + a];
            const int* aF = ip + IOFF_ADJF + a * MAXADJ;
            const int* aB = ip + IOFF_ADJB + a * MAXADJ;
            for (int b = t; b < S; b += 256) {
                float bt = ws[OFF_PHIE + a * S + b];
                for (int q = 0; q < cF; ++q) bt += ws[OFF_MSGF + aF[q] * S + b];
                for (int q = 0; q < cB; ++q) bt += ws[OFF_MSGB + aB[q] * S + b];
                out[a * S + b] = __expf(fminf(bt - ua - V[b], 0.f));
            }
        } else {
            for (int b = t; b < S; b += 256)
                out[a * S + b] = __expf(fminf(-uhi - V[b], 0.f));
        }
    }
}

// ---------------------------------------------------------------------------
extern "C" void kernel_launch(void* const* d_in, const int* in_sizes, int n_in,
                              void* d_out, int out_size, void* d_ws, size_t ws_size,
                              hipStream_t stream)
{
    const int*   E1f    = (const int*)d_in[0];
    const int*   E1b    = (const int*)d_in[1];
    const float* cost   = (const float*)d_in[3];
    const float* constr = (const float*)d_in[4];

    float* ws = (float*)d_ws;

    k_setup<<<64, 256, 0, stream>>>(E1f, E1b, cost, constr, ws);

    for (int step = 0; step < 8; ++step)
        k_step<<<455, 256, 0, stream>>>(ws, step);

    k_final<<<64, 256, 0, stream>>>(ws, (float*)d_out);
}

// Round 9
// 434.904 us; speedup vs baseline: 1.0278x; 1.0278x over previous
//
#include <hip/hip_runtime.h>
#include <math.h>

#define S      384
#define N0     192
#define NE     191
#define MAXADJ 16
#define E50    1.9287498e-22f   // exp(-50)

// float workspace offsets (round-5 layout)
#define OFF_W     0
#define OFF_WT    36864
#define OFF_PHIE  73728
#define OFF_MSGF  147456
#define OFF_MSGB  221184
#define OFF_MXF   294912
#define OFF_MXB   368640
#define OFF_SBT   442368
#define OFF_BASET 516096
#define OFF_U     589824
#define OFF_V     590016
#define OFF_MAXF  590400
#define OFF_MAXB  590592
#define OFF_HIF   590784
#define OFF_LOF   590976
#define OFF_HIB   591168
#define OFF_LOB   591360
#define OFF_UHI   591552
#define OFF_INT   591616
// int offsets relative to (int*)(ws + OFF_INT)
#define IOFF_DSTF 0
#define IOFF_DSTB 192
#define IOFF_CNTF 384
#define IOFF_CNTB 576
#define IOFF_ADJF 768
#define IOFF_ADJB (768 + 192*MAXADJ)
#define IOFF_SYNC (768 + 2*192*MAXADJ)   // 8 steps x 4 counters (unsigned)

#define AGT __HIP_MEMORY_SCOPE_AGENT

// coherent (LLC) scalar access — bypasses L1/L2, no fences needed
__device__ __forceinline__ float ldc(const float* p) {
    return __hip_atomic_load(p, __ATOMIC_RELAXED, AGT);
}
__device__ __forceinline__ void stc(float* p, float v) {
    __hip_atomic_store(p, v, __ATOMIC_RELAXED, AGT);
}

// block arrival: drain own stores (each wave), then one relaxed RMW at LLC
__device__ __forceinline__ void arrive(unsigned* c) {
    asm volatile("s_waitcnt vmcnt(0)" ::: "memory");
    __syncthreads();
    if (threadIdx.x == 0)
        __hip_atomic_fetch_add(c, 1u, __ATOMIC_RELAXED, AGT);
}
// consumer spin: relaxed atomic LOADs only (no RMW hammering)
__device__ __forceinline__ void wait_cnt(unsigned* c, unsigned tgt) {
    if (threadIdx.x == 0) {
        while (__hip_atomic_load(c, __ATOMIC_RELAXED, AGT) < tgt)
            __builtin_amdgcn_s_sleep(2);
    }
    __syncthreads();
}

// ---------------------------------------------------------------------------
__global__ __launch_bounds__(256) void k_setup(
    const int* __restrict__ E1f, const int* __restrict__ E1b,
    const float* __restrict__ cost, const float* __restrict__ constr,
    float* __restrict__ ws)
{
    int tid = blockIdx.x * 256 + threadIdx.x;
    int nt  = gridDim.x * 256;

    for (int idx = tid; idx < 192 * 192; idx += nt) {
        int k = idx / 192, s = idx % 192;
        float w = __expf(-50.f * (1.f - constr[idx]));
        ws[OFF_W + idx] = w;               // W[k][s]  (fwd GEMV weights)
        ws[OFF_WT + s * 192 + k] = w;      // WT[k][s] = W[s][k] (bwd)
    }
    for (int idx = tid; idx < 192 * S; idx += nt) {
        int j = idx / S, i = idx % S;
        ws[OFF_PHIE + idx] = (i < N0) ? -10.f * cost[j * N0 + i] : 0.f;
        ws[OFF_MSGF + idx] = 0.f;
        ws[OFF_MSGB + idx] = 0.f;
        ws[OFF_MXF + idx]  = 0.f;
        ws[OFF_MXB + idx]  = (j < NE) ? 1.f : 0.f;   // exp(0-0)=1
        ws[OFF_SBT + idx]  = 0.f;
        ws[OFF_BASET + idx] = 0.f;
    }
    for (int i = tid; i < S; i += nt) ws[OFF_V + i] = 0.f;
    for (int i = tid; i < 192; i += nt) {
        ws[OFF_U + i] = 0.f;
        ws[OFF_MAXF + i] = 0.f; ws[OFF_MAXB + i] = 0.f;
        ws[OFF_HIF + i] = 0.f;  ws[OFF_LOF + i] = 0.f;
        ws[OFF_HIB + i] = (i < NE) ? 192.f : 0.f;
        ws[OFF_LOB + i] = (i < NE) ? 192.f : 0.f;
    }
    if (tid == 0) ws[OFF_UHI] = 0.f;

    int* ip = (int*)(ws + OFF_INT);
    for (int e = tid; e < 192; e += nt) {
        ip[IOFF_DSTF + e] = (e < NE) ? E1f[2 * e + 1] : 0;
        ip[IOFF_DSTB + e] = (e < NE) ? E1b[2 * e + 1] : 0;
    }
    for (int b = tid; b < 192; b += nt) {
        int cf = 0, cb = 0;
        for (int e = 0; e < NE; ++e) {
            if (E1f[2 * e + 1] == b && cf < MAXADJ) ip[IOFF_ADJF + b * MAXADJ + cf++] = e;
            if (E1b[2 * e + 1] == b && cb < MAXADJ) ip[IOFF_ADJB + b * MAXADJ + cb++] = e;
        }
        ip[IOFF_CNTF + b] = cf;
        ip[IOFF_CNTB + b] = cb;
    }
    unsigned* sc = (unsigned*)(ip + IOFF_SYNC);
    for (int i = tid; i < 32; i += nt) sc[i] = 0u;
}

// ---------------------------------------------------------------------------
// persistent kernel: blocks [0,49) uv1 rows, block 48 also does uhi slot,
// [49,73) v, [73,264) msg (edge e = bid-73 handles fwd AND bwd)
__global__ __launch_bounds__(256) void k_iter(float* __restrict__ ws,
                                              float* __restrict__ out)
{
    const int bid = blockIdx.x, t = threadIdx.x;
    const int l = t & 63, w = t >> 6;
    int* ip = (int*)(ws + OFF_INT);
    unsigned* sync = (unsigned*)(ip + IOFF_SYNC);

    __shared__ float mx[192];
    __shared__ float Ul[192];
    __shared__ float red[256], red2[256];
    __shared__ float msh[16][17], ssh[16][17];

    for (int step = 0; step < 8; ++step) {
        unsigned* sc = sync + step * 4;

        if (bid < 49) {
            // ---- stage uv1 ----
            if (step > 0) wait_cnt(sync + (step - 1) * 4 + 3, NE);
            if (bid == 48) {
                if (w == 0) {
                    float m = -1e30f, x[6];
#pragma unroll
                    for (int q = 0; q < 6; ++q) {
                        x[q] = -ldc(ws + OFF_V + l + 64 * q);
                        m = fmaxf(m, x[q]);
                    }
#pragma unroll
                    for (int o = 32; o; o >>= 1) m = fmaxf(m, __shfl_xor(m, o, 64));
                    float sm = 0.f;
#pragma unroll
                    for (int q = 0; q < 6; ++q) sm += __expf(x[q] - m);
#pragma unroll
                    for (int o = 32; o; o >>= 1) sm += __shfl_xor(sm, o, 64);
                    if (l == 0) stc(ws + OFF_UHI, m + __logf(sm));
                }
            } else {
                int j = bid * 4 + w;
                int cF = ip[IOFF_CNTF + j], cB = ip[IOFF_CNTB + j];
                const int* aF = ip + IOFF_ADJF + j * MAXADJ;
                const int* aB = ip + IOFF_ADJB + j * MAXADJ;

                float sft[6] = {0,0,0,0,0,0}, sbt[6] = {0,0,0,0,0,0};
                for (int q = 0; q < cF; ++q) {
                    const float* mr = ws + OFF_MSGF + aF[q] * S;
#pragma unroll
                    for (int p = 0; p < 6; ++p) sft[p] += ldc(mr + l + 64 * p);
                }
                for (int q = 0; q < cB; ++q) {
                    const float* mr = ws + OFF_MSGB + aB[q] * S;
#pragma unroll
                    for (int p = 0; p < 6; ++p) sbt[p] += ldc(mr + l + 64 * p);
                }

                float x[6], m = -1e30f;
#pragma unroll
                for (int p = 0; p < 6; ++p) {
                    int i = l + 64 * p;
                    float bt = ws[OFF_PHIE + j * S + i] + sft[p] + sbt[p];
                    stc(ws + OFF_BASET + j * S + i, bt);
                    stc(ws + OFF_SBT + j * S + i, sbt[p]);
                    x[p] = bt - ldc(ws + OFF_V + i);
                    m = fmaxf(m, x[p]);
                }
#pragma unroll
                for (int o = 32; o; o >>= 1) m = fmaxf(m, __shfl_xor(m, o, 64));
                float sm = 0.f;
#pragma unroll
                for (int p = 0; p < 6; ++p) sm += __expf(x[p] - m);
#pragma unroll
                for (int o = 32; o; o >>= 1) sm += __shfl_xor(sm, o, 64);
                if (l == 0) stc(ws + OFF_U + j, m + __logf(sm));
            }
            arrive(&sc[0]);
        } else if (bid < 73) {
            // ---- stage v ----
            wait_cnt(&sc[0], 49u);
            if (t < 192) Ul[t] = ldc(ws + OFF_U + t);
            __syncthreads();

            int il = t & 15, jg = t >> 4;
            int i = (bid - 49) * 16 + il;

            float m = -1e30f, sm = 0.f;
            for (int j = jg; j < 192; j += 16) {
                float x = ldc(ws + OFF_BASET + j * S + i) - Ul[j];
                float mn = fmaxf(m, x);
                sm = sm * __expf(m - mn) + __expf(x - mn);
                m = mn;
            }
            msh[jg][il] = m; ssh[jg][il] = sm;
            __syncthreads();

            if (jg == 0) {
                float M = msh[0][il], Ss = ssh[0][il];
#pragma unroll
                for (int g = 1; g < 16; ++g) {
                    float m2 = msh[g][il], s2 = ssh[g][il];
                    float mn = fmaxf(M, m2);
                    Ss = Ss * __expf(M - mn) + s2 * __expf(m2 - mn);
                    M = mn;
                }
                float xt = __logf(192.f) - ldc(ws + OFF_UHI);
                float mn = fmaxf(M, xt);
                Ss = Ss * __expf(M - mn) + __expf(xt - mn);
                stc(ws + OFF_V + i, mn + __logf(Ss));
            }
            arrive(&sc[1]);
        } else {
            // ---- stage msg: fwd then bwd for edge e ----
            int e = bid - 73;
            for (int fwd = 1; fwd >= 0; --fwd) {
                wait_cnt(fwd ? &sc[1] : &sc[2], fwd ? 24u : (unsigned)NE);

                float* MSG  = ws + (fwd ? OFF_MSGF : OFF_MSGB);
                float* MX   = ws + (fwd ? OFF_MXF  : OFF_MXB);
                const float* MXin = ws + (fwd ? OFF_MXB : OFF_MXF);
                const float* Wm   = ws + (fwd ? OFF_W   : OFF_WT);

                float mPrev = fwd ? ws[OFF_MAXB + e] : ws[OFF_MAXF + e];
                float hi    = fwd ? ws[OFF_HIB + e]  : ws[OFF_HIF + e];
                float lo    = fwd ? ws[OFF_LOB + e]  : ws[OFF_LOF + e];
                float addLo = fwd ? hi : E50 * hi;
                float yHi   = fwd ? (hi + E50 * lo) : (lo + hi);
                float lyHi  = __logf(yHi);

                int d = fwd ? ip[IOFF_DSTF + e] : ip[IOFF_DSTB + e];
                float uD = ldc(ws + OFF_U + d);

                if (t < 192) mx[t] = MXin[e * S + t];
                __syncthreads();

                float acc = 0.f;
                if (t < 192) {
#pragma unroll 8
                    for (int k = 0; k < 192; ++k)
                        acc += Wm[k * 192 + t] * mx[k];
                }

                int s1 = t, s2 = t + 256;
                float bt1, bt2 = 0.f;
                if (fwd) {
                    bt1 = ldc(ws + OFF_BASET + d * S + s1);
                    if (s2 < S) bt2 = ldc(ws + OFF_BASET + d * S + s2);
                } else {
                    int cF = ip[IOFF_CNTF + d];
                    const int* aF = ip + IOFF_ADJF + d * MAXADJ;
                    bt1 = ws[OFF_PHIE + d * S + s1] + ldc(ws + OFF_SBT + d * S + s1);
                    if (s2 < S)
                        bt2 = ws[OFF_PHIE + d * S + s2] + ldc(ws + OFF_SBT + d * S + s2);
                    for (int q = 0; q < cF; ++q) {
                        const float* mr = ws + OFF_MSGF + aF[q] * S;
                        bt1 += ldc(mr + s1);
                        if (s2 < S) bt2 += ldc(mr + s2);
                    }
                }

                float v1 = ldc(ws + OFF_V + s1);
                float v2 = (s2 < S) ? ldc(ws + OFF_V + s2) : 0.f;

                float logy1 = (s1 < 192) ? __logf(acc + addLo) : lyHi;
                float x1 = 0.5f * (ldc(MSG + e * S + s1) + uD + v1 - bt1 + mPrev + logy1);
                float x2 = 1e30f;
                if (s2 < S) {
                    x2 = 0.5f * (ldc(MSG + e * S + s2) + uD + v2 - bt2 + mPrev + lyHi);
                    stc(MSG + e * S + s2, x2);
                }
                stc(MSG + e * S + s1, x1);

                red[t] = fminf(x1, x2);
                __syncthreads();
                for (int o = 128; o; o >>= 1) {
                    if (t < o) red[t] = fminf(red[t], red[t + o]);
                    __syncthreads();
                }
                float mn = red[0];
                __syncthreads();

                float mx1 = __expf(mn - x1);
                float mx2 = (s2 < S) ? __expf(mn - x2) : 0.f;
                MX[e * S + s1] = mx1;
                if (s2 < S) MX[e * S + s2] = mx2;
                if (t == 0) {
                    if (fwd) ws[OFF_MAXF + e] = -mn; else ws[OFF_MAXB + e] = -mn;
                }

                red[t]  = (t < 192) ? mx1 : 0.f;
                red2[t] = ((t >= 192) ? mx1 : 0.f) + mx2;
                __syncthreads();
                for (int o = 128; o; o >>= 1) {
                    if (t < o) { red[t] += red[t + o]; red2[t] += red2[t + o]; }
                    __syncthreads();
                }
                if (t == 0) {
                    if (fwd) { ws[OFF_LOF + e] = red[0]; ws[OFF_HIF + e] = red2[0]; }
                    else     { ws[OFF_LOB + e] = red[0]; ws[OFF_HIB + e] = red2[0]; }
                }
                __syncthreads();
                arrive(fwd ? &sc[2] : &sc[3]);
            }
        }
    }

    // ---- final: rows bid and bid+264 ----
    wait_cnt(sync + 7 * 4 + 3, NE);
    float uhi = ldc(ws + OFF_UHI);
    for (int a = bid; a < S; a += 264) {
        int s1 = t, s2 = t + 256;
        float v1 = ldc(ws + OFF_V + s1);
        float v2 = (s2 < S) ? ldc(ws + OFF_V + s2) : 0.f;
        if (a < 192) {
            float ua = ldc(ws + OFF_U + a);
            int cF = ip[IOFF_CNTF + a], cB = ip[IOFF_CNTB + a];
            const int* aF = ip + IOFF_ADJF + a * MAXADJ;
            const int* aB = ip + IOFF_ADJB + a * MAXADJ;
            float bt1 = ws[OFF_PHIE + a * S + s1];
            float bt2 = (s2 < S) ? ws[OFF_PHIE + a * S + s2] : 0.f;
            for (int q = 0; q < cF; ++q) {
                const float* mr = ws + OFF_MSGF + aF[q] * S;
                bt1 += ldc(mr + s1);
                if (s2 < S) bt2 += ldc(mr + s2);
            }
            for (int q = 0; q < cB; ++q) {
                const float* mr = ws + OFF_MSGB + aB[q] * S;
                bt1 += ldc(mr + s1);
                if (s2 < S) bt2 += ldc(mr + s2);
            }
            out[a * S + s1] = __expf(fminf(bt1 - ua - v1, 0.f));
            if (s2 < S) out[a * S + s2] = __expf(fminf(bt2 - ua - v2, 0.f));
        } else {
            out[a * S + s1] = __expf(fminf(-uhi - v1, 0.f));
            if (s2 < S) out[a * S + s2] = __expf(fminf(-uhi - v2, 0.f));
        }
    }
}

// ---------------------------------------------------------------------------
extern "C" void kernel_launch(void* const* d_in, const int* in_sizes, int n_in,
                              void* d_out, int out_size, void* d_ws, size_t ws_size,
                              hipStream_t stream)
{
    const int*   E1f    = (const int*)d_in[0];
    const int*   E1b    = (const int*)d_in[1];
    const float* cost   = (const float*)d_in[3];
    const float* constr = (const float*)d_in[4];

    float* ws   = (float*)d_ws;
    float* outp = (float*)d_out;

    k_setup<<<64, 256, 0, stream>>>(E1f, E1b, cost, constr, ws);

    void* args[] = { (void*)&ws, (void*)&outp };
    hipLaunchCooperativeKernel((const void*)k_iter, dim3(264), dim3(256),
                               args, 0, stream);
}

// Round 10
// 364.732 us; speedup vs baseline: 1.2256x; 1.1924x over previous
//
#include <hip/hip_runtime.h>
#include <math.h>

#define S      384
#define N0     192
#define NE     191
#define MAXADJ 16
#define E50    1.9287498e-22f   // exp(-50)

// float workspace offsets (round-5/9 layout)
#define OFF_W     0
#define OFF_WT    36864
#define OFF_PHIE  73728
#define OFF_MSGF  147456
#define OFF_MSGB  221184
#define OFF_MXF   294912
#define OFF_MXB   368640
#define OFF_SBT   442368
#define OFF_BASET 516096
#define OFF_U     589824
#define OFF_V     590016
#define OFF_MAXF  590400
#define OFF_MAXB  590592
#define OFF_HIF   590784
#define OFF_LOF   590976
#define OFF_HIB   591168
#define OFF_LOB   591360
#define OFF_UHI   591552
#define OFF_INT   591616
// int offsets relative to (int*)(ws + OFF_INT)
#define IOFF_DSTF 0
#define IOFF_DSTB 192
#define IOFF_CNTF 384
#define IOFF_CNTB 576
#define IOFF_ADJF 768
#define IOFF_ADJB (768 + 192*MAXADJ)
#define IOFF_FLG  (768 + 2*192*MAXADJ)   // 264 per-block flags (+pad to 512)

#define AGT __HIP_MEMORY_SCOPE_AGENT

// coherent (LLC) scalar access — bypasses L1/L2
__device__ __forceinline__ float ldc(const float* p) {
    return __hip_atomic_load(p, __ATOMIC_RELAXED, AGT);
}
__device__ __forceinline__ void stc(float* p, float v) {
    __hip_atomic_store(p, v, __ATOMIC_RELAXED, AGT);
}

// producer: drain own stores (per wave), then single flag STORE (no RMW)
__device__ __forceinline__ void arrive(unsigned* flg, int bid, unsigned stamp) {
    asm volatile("s_waitcnt vmcnt(0)" ::: "memory");
    __syncthreads();
    if (threadIdx.x == 0)
        __hip_atomic_store(&flg[bid], stamp, __ATOMIC_RELAXED, AGT);
}

// consumer: wave 0 polls [lo, lo+cnt) flags with vector loads + ballot
__device__ __forceinline__ void wait_range(unsigned* flg, int lo, int cnt,
                                           unsigned stamp) {
    if (threadIdx.x < 64) {
        int l = threadIdx.x;
        for (;;) {
            unsigned mn = 0xffffffffu;
            for (int q = l; q < cnt; q += 64) {
                unsigned f = __hip_atomic_load(&flg[lo + q], __ATOMIC_RELAXED, AGT);
                mn = (f < mn) ? f : mn;
            }
            if (__ballot(mn >= stamp) == ~0ull) break;
            __builtin_amdgcn_s_sleep(1);
        }
    }
    __syncthreads();
}

// ---------------------------------------------------------------------------
__global__ __launch_bounds__(256) void k_setup(
    const int* __restrict__ E1f, const int* __restrict__ E1b,
    const float* __restrict__ cost, const float* __restrict__ constr,
    float* __restrict__ ws)
{
    int tid = blockIdx.x * 256 + threadIdx.x;
    int nt  = gridDim.x * 256;

    for (int idx = tid; idx < 192 * 192; idx += nt) {
        int k = idx / 192, s = idx % 192;
        float w = __expf(-50.f * (1.f - constr[idx]));
        ws[OFF_W + idx] = w;               // W[k][s]
        ws[OFF_WT + s * 192 + k] = w;      // WT[k][s] = W[s][k]
    }
    for (int idx = tid; idx < 192 * S; idx += nt) {
        int j = idx / S, i = idx % S;
        ws[OFF_PHIE + idx] = (i < N0) ? -10.f * cost[j * N0 + i] : 0.f;
        ws[OFF_MSGF + idx] = 0.f;
        ws[OFF_MSGB + idx] = 0.f;
        ws[OFF_MXF + idx]  = 0.f;
        ws[OFF_MXB + idx]  = (j < NE) ? 1.f : 0.f;   // exp(0-0)=1
        ws[OFF_SBT + idx]  = 0.f;
        ws[OFF_BASET + idx] = 0.f;
    }
    for (int i = tid; i < S; i += nt) ws[OFF_V + i] = 0.f;
    for (int i = tid; i < 192; i += nt) {
        ws[OFF_U + i] = 0.f;
        ws[OFF_MAXF + i] = 0.f; ws[OFF_MAXB + i] = 0.f;
        ws[OFF_HIF + i] = 0.f;  ws[OFF_LOF + i] = 0.f;
        ws[OFF_HIB + i] = (i < NE) ? 192.f : 0.f;
        ws[OFF_LOB + i] = (i < NE) ? 192.f : 0.f;
    }
    if (tid == 0) ws[OFF_UHI] = 0.f;

    int* ip = (int*)(ws + OFF_INT);
    for (int e = tid; e < 192; e += nt) {
        ip[IOFF_DSTF + e] = (e < NE) ? E1f[2 * e + 1] : 0;
        ip[IOFF_DSTB + e] = (e < NE) ? E1b[2 * e + 1] : 0;
    }
    for (int b = tid; b < 192; b += nt) {
        int cf = 0, cb = 0;
        for (int e = 0; e < NE; ++e) {
            if (E1f[2 * e + 1] == b && cf < MAXADJ) ip[IOFF_ADJF + b * MAXADJ + cf++] = e;
            if (E1b[2 * e + 1] == b && cb < MAXADJ) ip[IOFF_ADJB + b * MAXADJ + cb++] = e;
        }
        ip[IOFF_CNTF + b] = cf;
        ip[IOFF_CNTB + b] = cb;
    }
    unsigned* flg = (unsigned*)(ip + IOFF_FLG);
    for (int i = tid; i < 512; i += nt) flg[i] = 0u;
}

// ---------------------------------------------------------------------------
// persistent kernel. blocks: [0,49) uv | [49,73) v | [73,264) msg (e = bid-73)
// stamps: uv done = 4*step+1, v = 4*step+2, msgf = 4*step+3, msgb = 4*step+4
__global__ __launch_bounds__(256) void k_iter(float* __restrict__ ws,
                                              float* __restrict__ out)
{
    const int bid = blockIdx.x, t = threadIdx.x;
    const int l = t & 63, w = t >> 6;
    int* ip = (int*)(ws + OFF_INT);
    unsigned* flg = (unsigned*)(ip + IOFF_FLG);

    __shared__ float mx[192];
    __shared__ float Ul[192];
    __shared__ float red[256], red2[256];
    __shared__ float msh[16][17], ssh[16][17];

    for (int step = 0; step < 8; ++step) {
        unsigned base = 4u * step;

        if (bid < 49) {
            // ---- stage uv1: wait msgb of prev step ----
            if (step > 0) wait_range(flg, 73, 191, base);
            if (bid == 48) {
                if (w == 0) {
                    float m = -1e30f, x[6];
#pragma unroll
                    for (int q = 0; q < 6; ++q) {
                        x[q] = -ldc(ws + OFF_V + l + 64 * q);
                        m = fmaxf(m, x[q]);
                    }
#pragma unroll
                    for (int o = 32; o; o >>= 1) m = fmaxf(m, __shfl_xor(m, o, 64));
                    float sm = 0.f;
#pragma unroll
                    for (int q = 0; q < 6; ++q) sm += __expf(x[q] - m);
#pragma unroll
                    for (int o = 32; o; o >>= 1) sm += __shfl_xor(sm, o, 64);
                    if (l == 0) stc(ws + OFF_UHI, m + __logf(sm));
                }
            } else {
                int j = bid * 4 + w;
                int cF = ip[IOFF_CNTF + j], cB = ip[IOFF_CNTB + j];
                const int* aF = ip + IOFF_ADJF + j * MAXADJ;
                const int* aB = ip + IOFF_ADJB + j * MAXADJ;

                float sft[6] = {0,0,0,0,0,0}, sbt[6] = {0,0,0,0,0,0};
                for (int q = 0; q < cF; ++q) {
                    const float* mr = ws + OFF_MSGF + aF[q] * S;
#pragma unroll
                    for (int p = 0; p < 6; ++p) sft[p] += ldc(mr + l + 64 * p);
                }
                for (int q = 0; q < cB; ++q) {
                    const float* mr = ws + OFF_MSGB + aB[q] * S;
#pragma unroll
                    for (int p = 0; p < 6; ++p) sbt[p] += ldc(mr + l + 64 * p);
                }

                float x[6], m = -1e30f;
#pragma unroll
                for (int p = 0; p < 6; ++p) {
                    int i = l + 64 * p;
                    float bt = ws[OFF_PHIE + j * S + i] + sft[p] + sbt[p];
                    stc(ws + OFF_BASET + j * S + i, bt);
                    stc(ws + OFF_SBT + j * S + i, sbt[p]);
                    x[p] = bt - ldc(ws + OFF_V + i);
                    m = fmaxf(m, x[p]);
                }
#pragma unroll
                for (int o = 32; o; o >>= 1) m = fmaxf(m, __shfl_xor(m, o, 64));
                float sm = 0.f;
#pragma unroll
                for (int p = 0; p < 6; ++p) sm += __expf(x[p] - m);
#pragma unroll
                for (int o = 32; o; o >>= 1) sm += __shfl_xor(sm, o, 64);
                if (l == 0) stc(ws + OFF_U + j, m + __logf(sm));
            }
            arrive(flg, bid, base + 1u);
        } else if (bid < 73) {
            // ---- stage v: wait all uv ----
            wait_range(flg, 0, 49, base + 1u);
            if (t < 192) Ul[t] = ldc(ws + OFF_U + t);
            __syncthreads();

            int il = t & 15, jg = t >> 4;
            int i = (bid - 49) * 16 + il;

            float m = -1e30f, sm = 0.f;
            for (int j = jg; j < 192; j += 16) {
                float x = ldc(ws + OFF_BASET + j * S + i) - Ul[j];
                float mn = fmaxf(m, x);
                sm = sm * __expf(m - mn) + __expf(x - mn);
                m = mn;
            }
            msh[jg][il] = m; ssh[jg][il] = sm;
            __syncthreads();

            if (jg == 0) {
                float M = msh[0][il], Ss = ssh[0][il];
#pragma unroll
                for (int g = 1; g < 16; ++g) {
                    float m2 = msh[g][il], s2 = ssh[g][il];
                    float mn = fmaxf(M, m2);
                    Ss = Ss * __expf(M - mn) + s2 * __expf(m2 - mn);
                    M = mn;
                }
                float xt = __logf(192.f) - ldc(ws + OFF_UHI);
                float mn = fmaxf(M, xt);
                Ss = Ss * __expf(M - mn) + __expf(xt - mn);
                stc(ws + OFF_V + i, mn + __logf(Ss));
            }
            arrive(flg, bid, base + 2u);
        } else {
            // ---- stage msg: fwd then bwd for edge e ----
            int e = bid - 73;
            for (int fwd = 1; fwd >= 0; --fwd) {
                if (fwd) wait_range(flg, 49, 24, base + 2u);
                else     wait_range(flg, 73, 191, base + 3u);

                float* MSG  = ws + (fwd ? OFF_MSGF : OFF_MSGB);
                float* MX   = ws + (fwd ? OFF_MXF  : OFF_MXB);
                const float* MXin = ws + (fwd ? OFF_MXB : OFF_MXF);
                const float* Wm   = ws + (fwd ? OFF_W   : OFF_WT);

                float mPrev = fwd ? ws[OFF_MAXB + e] : ws[OFF_MAXF + e];
                float hi    = fwd ? ws[OFF_HIB + e]  : ws[OFF_HIF + e];
                float lo    = fwd ? ws[OFF_LOB + e]  : ws[OFF_LOF + e];
                float addLo = fwd ? hi : E50 * hi;
                float yHi   = fwd ? (hi + E50 * lo) : (lo + hi);
                float lyHi  = __logf(yHi);

                int d = fwd ? ip[IOFF_DSTF + e] : ip[IOFF_DSTB + e];
                float uD = ldc(ws + OFF_U + d);

                if (t < 192) mx[t] = MXin[e * S + t];
                __syncthreads();

                float acc = 0.f;
                if (t < 192) {
#pragma unroll 8
                    for (int k = 0; k < 192; ++k)
                        acc += Wm[k * 192 + t] * mx[k];
                }

                int s1 = t, s2 = t + 256;
                float bt1, bt2 = 0.f;
                if (fwd) {
                    bt1 = ldc(ws + OFF_BASET + d * S + s1);
                    if (s2 < S) bt2 = ldc(ws + OFF_BASET + d * S + s2);
                } else {
                    int cF = ip[IOFF_CNTF + d];
                    const int* aF = ip + IOFF_ADJF + d * MAXADJ;
                    bt1 = ws[OFF_PHIE + d * S + s1] + ldc(ws + OFF_SBT + d * S + s1);
                    if (s2 < S)
                        bt2 = ws[OFF_PHIE + d * S + s2] + ldc(ws + OFF_SBT + d * S + s2);
                    for (int q = 0; q < cF; ++q) {
                        const float* mr = ws + OFF_MSGF + aF[q] * S;
                        bt1 += ldc(mr + s1);
                        if (s2 < S) bt2 += ldc(mr + s2);
                    }
                }

                float v1 = ldc(ws + OFF_V + s1);
                float v2 = (s2 < S) ? ldc(ws + OFF_V + s2) : 0.f;

                float logy1 = (s1 < 192) ? __logf(acc + addLo) : lyHi;
                float x1 = 0.5f * (ldc(MSG + e * S + s1) + uD + v1 - bt1 + mPrev + logy1);
                float x2 = 1e30f;
                if (s2 < S) {
                    x2 = 0.5f * (ldc(MSG + e * S + s2) + uD + v2 - bt2 + mPrev + lyHi);
                    stc(MSG + e * S + s2, x2);
                }
                stc(MSG + e * S + s1, x1);

                red[t] = fminf(x1, x2);
                __syncthreads();
                for (int o = 128; o; o >>= 1) {
                    if (t < o) red[t] = fminf(red[t], red[t + o]);
                    __syncthreads();
                }
                float mn = red[0];
                __syncthreads();

                float mx1 = __expf(mn - x1);
                float mx2 = (s2 < S) ? __expf(mn - x2) : 0.f;
                MX[e * S + s1] = mx1;
                if (s2 < S) MX[e * S + s2] = mx2;
                if (t == 0) {
                    if (fwd) ws[OFF_MAXF + e] = -mn; else ws[OFF_MAXB + e] = -mn;
                }

                red[t]  = (t < 192) ? mx1 : 0.f;
                red2[t] = ((t >= 192) ? mx1 : 0.f) + mx2;
                __syncthreads();
                for (int o = 128; o; o >>= 1) {
                    if (t < o) { red[t] += red[t + o]; red2[t] += red2[t + o]; }
                    __syncthreads();
                }
                if (t == 0) {
                    if (fwd) { ws[OFF_LOF + e] = red[0]; ws[OFF_HIF + e] = red2[0]; }
                    else     { ws[OFF_LOB + e] = red[0]; ws[OFF_HIB + e] = red2[0]; }
                }
                __syncthreads();
                arrive(flg, bid, base + (fwd ? 3u : 4u));
            }
        }
    }

    // ---- final: wait msgb of step 7; rows a = bid, bid+264 ----
    wait_range(flg, 73, 191, 32u);
    float uhi = ldc(ws + OFF_UHI);
    for (int a = bid; a < S; a += 264) {
        int s1 = t, s2 = t + 256;
        float v1 = ldc(ws + OFF_V + s1);
        float v2 = (s2 < S) ? ldc(ws + OFF_V + s2) : 0.f;
        if (a < 192) {
            float ua = ldc(ws + OFF_U + a);
            int cF = ip[IOFF_CNTF + a], cB = ip[IOFF_CNTB + a];
            const int* aF = ip + IOFF_ADJF + a * MAXADJ;
            const int* aB = ip + IOFF_ADJB + a * MAXADJ;
            float bt1 = ws[OFF_PHIE + a * S + s1];
            float bt2 = (s2 < S) ? ws[OFF_PHIE + a * S + s2] : 0.f;
            for (int q = 0; q < cF; ++q) {
                const float* mr = ws + OFF_MSGF + aF[q] * S;
                bt1 += ldc(mr + s1);
                if (s2 < S) bt2 += ldc(mr + s2);
            }
            for (int q = 0; q < cB; ++q) {
                const float* mr = ws + OFF_MSGB + aB[q] * S;
                bt1 += ldc(mr + s1);
                if (s2 < S) bt2 += ldc(mr + s2);
            }
            out[a * S + s1] = __expf(fminf(bt1 - ua - v1, 0.f));
            if (s2 < S) out[a * S + s2] = __expf(fminf(bt2 - ua - v2, 0.f));
        } else {
            out[a * S + s1] = __expf(fminf(-uhi - v1, 0.f));
            if (s2 < S) out[a * S + s2] = __expf(fminf(-uhi - v2, 0.f));
        }
    }
}

// ---------------------------------------------------------------------------
extern "C" void kernel_launch(void* const* d_in, const int* in_sizes, int n_in,
                              void* d_out, int out_size, void* d_ws, size_t ws_size,
                              hipStream_t stream)
{
    const int*   E1f    = (const int*)d_in[0];
    const int*   E1b    = (const int*)d_in[1];
    const float* cost   = (const float*)d_in[3];
    const float* constr = (const float*)d_in[4];

    float* ws   = (float*)d_ws;
    float* outp = (float*)d_out;

    k_setup<<<64, 256, 0, stream>>>(E1f, E1b, cost, constr, ws);

    void* args[] = { (void*)&ws, (void*)&outp };
    hipLaunchCooperativeKernel((const void*)k_iter, dim3(264), dim3(256),
                               args, 0, stream);
}

// Round 12
// 361.562 us; speedup vs baseline: 1.2363x; 1.0088x over previous
//
#include <hip/hip_runtime.h>
#include <math.h>

#define S      384
#define N0     192
#define NE     191
#define MAXADJ 16
#define E50    1.9287498e-22f   // exp(-50)

// float workspace offsets
#define OFF_W     0
#define OFF_WT    36864
#define OFF_PHIE  73728
#define OFF_MSGF  147456
#define OFF_MSGB  221184
#define OFF_MXF   294912
#define OFF_MXB   368640
#define OFF_SBT   442368
#define OFF_BASET 516096
#define OFF_U     589824
#define OFF_V     590016
#define OFF_MAXF  590400
#define OFF_MAXB  590592
#define OFF_HIF   590784
#define OFF_LOF   590976
#define OFF_HIB   591168
#define OFF_LOB   591360
#define OFF_UHI   591552
#define OFF_PARTM 591616       // [48][384] per-row-block v-partial max
#define OFF_PARTS 610048       // [48][384] per-row-block v-partial sum
#define OFF_INT   628480
// int offsets relative to (int*)(ws + OFF_INT)
#define IOFF_DSTF 0
#define IOFF_DSTB 192
#define IOFF_CNTF 384
#define IOFF_CNTB 576
#define IOFF_ADJF 768
#define IOFF_ADJB (768 + 192*MAXADJ)

// ---------------------------------------------------------------------------
__global__ __launch_bounds__(256) void k_setup(
    const int* __restrict__ E1f, const int* __restrict__ E1b,
    const float* __restrict__ cost, const float* __restrict__ constr,
    float* __restrict__ ws)
{
    int tid = blockIdx.x * 256 + threadIdx.x;
    int nt  = gridDim.x * 256;

    for (int idx = tid; idx < 192 * 192; idx += nt) {
        int k = idx / 192, s = idx % 192;
        float w = __expf(-50.f * (1.f - constr[idx]));
        ws[OFF_W + idx] = w;               // W[k][s]  (fwd GEMV weights)
        ws[OFF_WT + s * 192 + k] = w;      // WT[k][s] = W[s][k] (bwd)
    }
    for (int idx = tid; idx < 192 * S; idx += nt) {
        int j = idx / S, i = idx % S;
        ws[OFF_PHIE + idx] = (i < N0) ? -10.f * cost[j * N0 + i] : 0.f;
        ws[OFF_MSGF + idx] = 0.f;
        ws[OFF_MSGB + idx] = 0.f;
        ws[OFF_MXF + idx]  = 0.f;
        ws[OFF_MXB + idx]  = (j < NE) ? 1.f : 0.f;   // exp(0-0)=1
    }
    for (int i = tid; i < S; i += nt) ws[OFF_V + i] = 0.f;
    for (int i = tid; i < 192; i += nt) {
        ws[OFF_U + i] = 0.f;
        ws[OFF_MAXF + i] = 0.f; ws[OFF_MAXB + i] = 0.f;
        ws[OFF_HIF + i] = 0.f;  ws[OFF_LOF + i] = 0.f;
        ws[OFF_HIB + i] = (i < NE) ? 192.f : 0.f;
        ws[OFF_LOB + i] = (i < NE) ? 192.f : 0.f;
    }
    if (tid == 0) ws[OFF_UHI] = 0.f;

    int* ip = (int*)(ws + OFF_INT);
    for (int e = tid; e < 192; e += nt) {
        ip[IOFF_DSTF + e] = (e < NE) ? E1f[2 * e + 1] : 0;
        ip[IOFF_DSTB + e] = (e < NE) ? E1b[2 * e + 1] : 0;
    }
    for (int b = tid; b < 192; b += nt) {
        int cf = 0, cb = 0;
        for (int e = 0; e < NE; ++e) {
            if (E1f[2 * e + 1] == b && cf < MAXADJ) ip[IOFF_ADJF + b * MAXADJ + cf++] = e;
            if (E1b[2 * e + 1] == b && cb < MAXADJ) ip[IOFF_ADJB + b * MAXADJ + cb++] = e;
        }
        ip[IOFF_CNTF + b] = cf;
        ip[IOFF_CNTB + b] = cb;
    }
}

// ---------------------------------------------------------------------------
// K1: per row j<192 (one wave each): gather SFT/SBT from msgs, rewrite
//     BASET[j] = phie_neg[j] + sft + sbt, store SBT[j], u[j] = LSE_i(BT-V).
//     Then write per-block v-partials over its 4 rows: PARTM/PARTS[bid][i].
//     Block 48: uhi = LSE_i(-V[i]).
__global__ __launch_bounds__(256) void k_uv1(float* __restrict__ ws)
{
    __shared__ float xm[4][384];
    int bid = blockIdx.x, t = threadIdx.x;
    int l = t & 63, w = t >> 6;
    const float* V = ws + OFF_V;

    if (bid == 48) {
        if (w == 0) {
            float m = -1e30f, x[6];
#pragma unroll
            for (int q = 0; q < 6; ++q) { x[q] = -V[l + 64 * q]; m = fmaxf(m, x[q]); }
#pragma unroll
            for (int o = 32; o; o >>= 1) m = fmaxf(m, __shfl_xor(m, o, 64));
            float sm = 0.f;
#pragma unroll
            for (int q = 0; q < 6; ++q) sm += __expf(x[q] - m);
#pragma unroll
            for (int o = 32; o; o >>= 1) sm += __shfl_xor(sm, o, 64);
            if (l == 0) ws[OFF_UHI] = m + __logf(sm);
        }
        return;
    }

    int j = bid * 4 + w;                    // 48 blocks x 4 waves = 192 rows
    const int* ip = (const int*)(ws + OFF_INT);
    int cF = ip[IOFF_CNTF + j], cB = ip[IOFF_CNTB + j];
    const int* aF = ip + IOFF_ADJF + j * MAXADJ;
    const int* aB = ip + IOFF_ADJB + j * MAXADJ;

    float sft[6] = {0,0,0,0,0,0}, sbt[6] = {0,0,0,0,0,0};
    for (int q = 0; q < cF; ++q) {
        const float* mr = ws + OFF_MSGF + aF[q] * S;
#pragma unroll
        for (int p = 0; p < 6; ++p) sft[p] += mr[l + 64 * p];
    }
    for (int q = 0; q < cB; ++q) {
        const float* mr = ws + OFF_MSGB + aB[q] * S;
#pragma unroll
        for (int p = 0; p < 6; ++p) sbt[p] += mr[l + 64 * p];
    }

    float bt[6], x[6], m = -1e30f;
#pragma unroll
    for (int p = 0; p < 6; ++p) {
        int i = l + 64 * p;
        bt[p] = ws[OFF_PHIE + j * S + i] + sft[p] + sbt[p];
        ws[OFF_BASET + j * S + i] = bt[p];
        ws[OFF_SBT + j * S + i]   = sbt[p];
        x[p] = bt[p] - V[i];
        m = fmaxf(m, x[p]);
    }
#pragma unroll
    for (int o = 32; o; o >>= 1) m = fmaxf(m, __shfl_xor(m, o, 64));
    float sm = 0.f;
#pragma unroll
    for (int p = 0; p < 6; ++p) sm += __expf(x[p] - m);
#pragma unroll
    for (int o = 32; o; o >>= 1) sm += __shfl_xor(sm, o, 64);
    float uj = m + __logf(sm);
    if (l == 0) ws[OFF_U + j] = uj;

    // v-partial for this block's 4 rows: xm[w][i] = bt - u_j
#pragma unroll
    for (int p = 0; p < 6; ++p) xm[w][l + 64 * p] = bt[p] - uj;
    __syncthreads();
    for (int i = t; i < S; i += 256) {
        float a0 = xm[0][i], a1 = xm[1][i], a2 = xm[2][i], a3 = xm[3][i];
        float M = fmaxf(fmaxf(a0, a1), fmaxf(a2, a3));
        float Sx = __expf(a0 - M) + __expf(a1 - M) + __expf(a2 - M) + __expf(a3 - M);
        ws[OFF_PARTM + bid * S + i] = M;
        ws[OFF_PARTS + bid * S + i] = Sx;
    }
}

// ---------------------------------------------------------------------------
// K2/K3: msg update with fused GEMV + colsum. One block per edge.
//  fwd=1: merge the 48 v-partials (+tail) -> v for own columns; e==0 publishes V.
//  fwd: y_lo[s] = sum_k W[k][s]*MXB[e][k] ; bt = BASET[d]
//  bwd: y_lo[s] = sum_k WT[k][s]*MXF[e][k]; bt = PHIE[d]+SBT[d]+gather(MSGF,adjF[d])
__global__ __launch_bounds__(256) void k_msg(float* __restrict__ ws, int fwd)
{
    __shared__ float mx[192];
    __shared__ float red[256], red2[256];
    int e = blockIdx.x, t = threadIdx.x;
    const int* ip = (const int*)(ws + OFF_INT);

    float* MSG  = ws + (fwd ? OFF_MSGF : OFF_MSGB);
    float* MX   = ws + (fwd ? OFF_MXF  : OFF_MXB);
    const float* MXin = ws + (fwd ? OFF_MXB : OFF_MXF);
    const float* Wm   = ws + (fwd ? OFF_W   : OFF_WT);

    float mPrev = fwd ? ws[OFF_MAXB + e] : ws[OFF_MAXF + e];
    float hi    = fwd ? ws[OFF_HIB + e]  : ws[OFF_HIF + e];
    float lo    = fwd ? ws[OFF_LOB + e]  : ws[OFF_LOF + e];
    float addLo = fwd ? hi : E50 * hi;
    float yHi   = fwd ? (hi + E50 * lo) : (lo + hi);
    float lyHi  = __logf(yHi);

    int d = fwd ? ip[IOFF_DSTF + e] : ip[IOFF_DSTB + e];
    float uD = ws[OFF_U + d];

    if (t < 192) mx[t] = MXin[e * S + t];
    __syncthreads();

    int s1 = t, s2 = t + 256;

    // v for this thread's columns
    float v1, v2 = 0.f;
    if (fwd) {
        float M1 = -1e30f, S1v = 0.f, M2 = -1e30f, S2v = 0.f;
#pragma unroll 4
        for (int p = 0; p < 48; ++p) {
            float pm = ws[OFF_PARTM + p * S + s1];
            float psv = ws[OFF_PARTS + p * S + s1];
            float mn = fmaxf(M1, pm);
            S1v = S1v * __expf(M1 - mn) + psv * __expf(pm - mn);
            M1 = mn;
            if (s2 < S) {
                float pm2 = ws[OFF_PARTM + p * S + s2];
                float ps2 = ws[OFF_PARTS + p * S + s2];
                float mn2 = fmaxf(M2, pm2);
                S2v = S2v * __expf(M2 - mn2) + ps2 * __expf(pm2 - mn2);
                M2 = mn2;
            }
        }
        float xt = __logf(192.f) - ws[OFF_UHI];
        float mn = fmaxf(M1, xt);
        S1v = S1v * __expf(M1 - mn) + __expf(xt - mn);
        v1 = mn + __logf(S1v);
        if (s2 < S) {
            float mn2 = fmaxf(M2, xt);
            S2v = S2v * __expf(M2 - mn2) + __expf(xt - mn2);
            v2 = mn2 + __logf(S2v);
        }
        if (e == 0) {                     // publish V for bwd/uv1/final
            ws[OFF_V + s1] = v1;
            if (s2 < S) ws[OFF_V + s2] = v2;
        }
    } else {
        v1 = ws[OFF_V + s1];
        if (s2 < S) v2 = ws[OFF_V + s2];
    }

    // GEMV: y = sum_k Wm[k][s] * mx[k], thread t owns s=t (t<192)
    float acc = 0.f;
    if (t < 192) {
#pragma unroll 8
        for (int k = 0; k < 192; ++k)
            acc += Wm[k * 192 + t] * mx[k];
    }

    // bt for this thread's two columns
    float bt1, bt2 = 0.f;
    if (fwd) {
        bt1 = ws[OFF_BASET + d * S + s1];
        if (s2 < S) bt2 = ws[OFF_BASET + d * S + s2];
    } else {
        int cF = ip[IOFF_CNTF + d];
        const int* aF = ip + IOFF_ADJF + d * MAXADJ;
        bt1 = ws[OFF_PHIE + d * S + s1] + ws[OFF_SBT + d * S + s1];
        if (s2 < S) bt2 = ws[OFF_PHIE + d * S + s2] + ws[OFF_SBT + d * S + s2];
        for (int q = 0; q < cF; ++q) {
            const float* mr = ws + OFF_MSGF + aF[q] * S;
            bt1 += mr[s1];
            if (s2 < S) bt2 += mr[s2];
        }
    }

    float logy1 = (s1 < 192) ? __logf(acc + addLo) : lyHi;
    float x1 = 0.5f * (MSG[e * S + s1] + uD + v1 - bt1 + mPrev + logy1);
    float x2 = 1e30f;
    if (s2 < S) {
        x2 = 0.5f * (MSG[e * S + s2] + uD + v2 - bt2 + mPrev + lyHi);
        MSG[e * S + s2] = x2;
    }
    MSG[e * S + s1] = x1;

    red[t] = fminf(x1, x2);
    __syncthreads();
    for (int o = 128; o; o >>= 1) {
        if (t < o) red[t] = fminf(red[t], red[t + o]);
        __syncthreads();
    }
    float mn = red[0];
    __syncthreads();

    float mx1 = __expf(mn - x1);
    float mx2 = (s2 < S) ? __expf(mn - x2) : 0.f;
    MX[e * S + s1] = mx1;
    if (s2 < S) MX[e * S + s2] = mx2;
    if (t == 0) {
        if (fwd) ws[OFF_MAXF + e] = -mn; else ws[OFF_MAXB + e] = -mn;
    }

    red[t]  = (t < 192) ? mx1 : 0.f;
    red2[t] = ((t >= 192) ? mx1 : 0.f) + mx2;
    __syncthreads();
    for (int o = 128; o; o >>= 1) {
        if (t < o) { red[t] += red[t + o]; red2[t] += red2[t + o]; }
        __syncthreads();
    }
    if (t == 0) {
        if (fwd) { ws[OFF_LOF + e] = red[0]; ws[OFF_HIF + e] = red2[0]; }
        else     { ws[OFF_LOB + e] = red[0]; ws[OFF_HIB + e] = red2[0]; }
    }
}

// final: out[a][b] = exp(min(btFinal[a][b] - U[a] - V[b], 0))
//   btFinal = phie + gather(MSGF) + gather(MSGB); rows a>=192: bt=0, U=uhi
__global__ __launch_bounds__(256) void k_final(const float* __restrict__ ws,
                                               float* __restrict__ out)
{
    int t = threadIdx.x;
    const int* ip = (const int*)(ws + OFF_INT);
    const float* V = ws + OFF_V;
    float uhi = ws[OFF_UHI];

    for (int a = blockIdx.x * 6; a < blockIdx.x * 6 + 6; ++a) {
        if (a < 192) {
            float ua = ws[OFF_U + a];
            int cF = ip[IOFF_CNTF + a], cB = ip[IOFF_CNTB + a];
            const int* aF = ip + IOFF_ADJF + a * MAXADJ;
            const int* aB = ip + IOFF_ADJB + a * MAXADJ;
            for (int b = t; b < S; b += 256) {
                float bt = ws[OFF_PHIE + a * S + b];
                for (int q = 0; q < cF; ++q) bt += ws[OFF_MSGF + aF[q] * S + b];
                for (int q = 0; q < cB; ++q) bt += ws[OFF_MSGB + aB[q] * S + b];
                out[a * S + b] = __expf(fminf(bt - ua - V[b], 0.f));
            }
        } else {
            for (int b = t; b < S; b += 256)
                out[a * S + b] = __expf(fminf(-uhi - V[b], 0.f));
        }
    }
}

// ---------------------------------------------------------------------------
extern "C" void kernel_launch(void* const* d_in, const int* in_sizes, int n_in,
                              void* d_out, int out_size, void* d_ws, size_t ws_size,
                              hipStream_t stream)
{
    const int*   E1f    = (const int*)d_in[0];
    const int*   E1b    = (const int*)d_in[1];
    const float* cost   = (const float*)d_in[3];
    const float* constr = (const float*)d_in[4];

    float* ws = (float*)d_ws;

    k_setup<<<64, 256, 0, stream>>>(E1f, E1b, cost, constr, ws);

    for (int step = 0; step < 8; ++step) {
        k_uv1<<<49, 256, 0, stream>>>(ws);
        k_msg<<<NE, 256, 0, stream>>>(ws, 1);
        k_msg<<<NE, 256, 0, stream>>>(ws, 0);
    }

    k_final<<<64, 256, 0, stream>>>(ws, (float*)d_out);
}